// Round 4
// baseline (159.770 us; speedup 1.0000x reference)
//
#include <hip/hip_runtime.h>
#include <hip/hip_bf16.h>

// Problem: out[b,l,:] = code[b,l,:] @ W[l]   (B=256, L=64, C=256, HW=1024, fp32)
#define B_  256
#define L_  64
#define C_  256
#define HW_ 1024

typedef float  floatx4 __attribute__((ext_vector_type(4)));
typedef __bf16 bf16x8  __attribute__((ext_vector_type(8)));
typedef __bf16 bf16x4  __attribute__((ext_vector_type(4)));

// Barrier that does NOT drain outstanding global loads (vmcnt): only LDS ops
// must be visible across the barrier; register prefetch stays in flight.
#define BARRIER_LDS() asm volatile("s_waitcnt lgkmcnt(0)\n\ts_barrier" ::: "memory")

// ROUND 4: BK=128 (2 K-phases instead of 4), geometry otherwise = R0 (the
// fastest measured structure). Model from R0-R3 evidence:
//   time ~ max(load_bytes/8TB/s, phases * ~2.3us fixed phase cost)
// R0 = 43.6us vs 33.5us byte-floor -> ~10us of per-phase overhead over 4
// phases. Halving phase count (fatter phases: 32 MFMA/wave between barriers)
// attacks that term with zero change to bytes, fragments, or epilogue.
// Registers sized to keep 4 waves/SIMD (2 resident blocks/CU -- R3 proved
// 1 block/CU latency-serializes): staging 64 VGPR + acc 32 + misc ~= 128,
// forced by __launch_bounds__(512,4). LDS 64 KB -> 2 blocks by LDS.
//
// LDS layout (both tiles): [row][128 k] bf16, 256 B rows, XOR swizzle on the
// low-3 bits of the 16B-chunk index (row-half preserved):
//   byte(row, k) = row*256 + ((cc&8)<<4) + (((cc^g(row))&7)<<4) + (2k mod 16)
//   cc = k>>3, g(r) = (r ^ (r>>2)) & 7   -- same verified scheme as R0,
// extended to 16 chunks/row (swizzle within each 128-B half-row).
__device__ __forceinline__ int bswz(int r) { return (r ^ (r >> 2)) & 7; }
__device__ __forceinline__ int lds_addr(int row, int cc) {
    return row * 256 + ((cc & 8) << 4) + ((((cc ^ bswz(row)) & 7)) << 4);
}

__global__ __launch_bounds__(512, 4)
void gld_mfma_kernel(const float* __restrict__ code,
                     const float* __restrict__ W,
                     float* __restrict__ out)
{
    const int tid = threadIdx.x;

    // XCD swizzle: id = ll + 8*(m + 2n + 16*lh), l = 8*lh + ll (as R0).
    const int id  = blockIdx.x;
    const int ll  = id & 7;
    const int inr = id >> 3;
    const int m0  = (inr & 1) * 128;        // batch rows
    const int n0  = ((inr >> 1) & 7) * 128; // HW cols
    const int l   = (inr >> 4) * 8 + ll;    // filter

    __shared__ unsigned char Alds[128 * 256];   // A tile [m][128k] bf16, swizzled (32 KB)
    __shared__ unsigned char Blds[128 * 256];   // B tile [n][128k] bf16, swizzled (32 KB)

    const int lane = tid & 63;
    const int wave = tid >> 6;          // 0..7
    const int wm = (wave >> 2) * 64;    // 0,64
    const int wn = (wave & 3) * 32;     // 0,32,64,96

    floatx4 acc[4][2];
    #pragma unroll
    for (int i = 0; i < 4; ++i)
        #pragma unroll
        for (int j = 0; j < 2; ++j)
            acc[i][j] = (floatx4)0.0f;

    // A staging: 128 rows x 128 k fp32. Thread: float4 at k=4*a_t of rows
    // p*16 + a_row8, p=0..7. Per instr: 2 x 512 B contiguous runs (fully
    // coalesced, each 128B line covered exactly once).
    const int a_t    = tid & 31;         // k-quad 0..31 (k = 4*a_t)
    const int a_row8 = tid >> 5;         // 0..15
    // B staging: 128 k-rows x 128 n fp32. Thread owns 4n x 8k micro-tile:
    // 8 float4 at consecutive k-rows. Per instr: 2 x 512 B runs.
    const int b_i = tid & 31;            // n-quad (n = 4*b_i + j)
    const int b_k = tid >> 5;            // k-octet 0..15 (k = 8*b_k ..+7)

    const float* aBase = code + (size_t)m0 * (L_ * C_) + (size_t)l * C_ + 4 * a_t;
    const float* wBase = W + (size_t)l * (C_ * HW_) + (size_t)(8 * b_k) * HW_ + n0 + 4 * b_i;

    floatx4 Areg[8];   // depth-1 (depth-2 measured neutral, round 1)
    floatx4 Breg[8];   // depth-1

    // ---- prologue: A(0), B(0) ----
    #pragma unroll
    for (int p = 0; p < 8; ++p)
        Areg[p] = *(const floatx4*)(aBase + (size_t)(p * 16 + a_row8) * (L_ * C_));
    #pragma unroll
    for (int r = 0; r < 8; ++r)
        Breg[r] = *(const floatx4*)(wBase + (size_t)r * HW_);

    #pragma unroll
    for (int kb = 0; kb < C_; kb += 128) {
        // ---- stage A: bf16x4 at chunk cc = a_t>>1, byte-off 8*(a_t&1).
        // (vmcnt waits here cover loads issued a full phase ago)
        #pragma unroll
        for (int p = 0; p < 8; ++p) {
            bf16x4 h;
            h.x = (__bf16)Areg[p].x; h.y = (__bf16)Areg[p].y;
            h.z = (__bf16)Areg[p].z; h.w = (__bf16)Areg[p].w;
            *(bf16x4*)&Alds[lds_addr(p * 16 + a_row8, a_t >> 1) + ((a_t & 1) << 3)] = h;
        }
        // ---- stage B: register 8x4 transpose -> k-contiguous bf16x8 ----
        #pragma unroll
        for (int j = 0; j < 4; ++j) {
            bf16x8 h;
            h[0] = (__bf16)Breg[0][j]; h[1] = (__bf16)Breg[1][j];
            h[2] = (__bf16)Breg[2][j]; h[3] = (__bf16)Breg[3][j];
            h[4] = (__bf16)Breg[4][j]; h[5] = (__bf16)Breg[5][j];
            h[6] = (__bf16)Breg[6][j]; h[7] = (__bf16)Breg[7][j];
            *(bf16x8*)&Blds[lds_addr(4 * b_i + j, b_k)] = h;
        }

        // ---- issue prefetch for kb+128 (stays in flight across barriers) ----
        if (kb + 128 < C_) {
            #pragma unroll
            for (int p = 0; p < 8; ++p)
                Areg[p] = *(const floatx4*)(aBase + (size_t)(p * 16 + a_row8) * (L_ * C_) + (kb + 128));
            #pragma unroll
            for (int r = 0; r < 8; ++r)
                Breg[r] = *(const floatx4*)(wBase + (size_t)(kb + 128 + r) * HW_);
        }

        BARRIER_LDS();   // LDS writes visible; vmcnt NOT drained

        // ---- compute: 4 k-steps of 32, 8 MFMA each (32 MFMA/wave/phase) ----
        #pragma unroll
        for (int ks = 0; ks < 4; ++ks) {
            bf16x8 af[4], bfr[2];
            const int cc = ks * 4 + (lane >> 4);     // chunk of koff = ks*32+(lane>>4)*8
            #pragma unroll
            for (int i = 0; i < 4; ++i)
                af[i] = *(const bf16x8*)&Alds[lds_addr(wm + i * 16 + (lane & 15), cc)];
            #pragma unroll
            for (int j = 0; j < 2; ++j)
                bfr[j] = *(const bf16x8*)&Blds[lds_addr(wn + j * 16 + (lane & 15), cc)];
            #pragma unroll
            for (int i = 0; i < 4; ++i)
                #pragma unroll
                for (int j = 0; j < 2; ++j)
                    acc[i][j] = __builtin_amdgcn_mfma_f32_16x16x32_bf16(af[i], bfr[j], acc[i][j], 0, 0, 0);
        }

        BARRIER_LDS();   // all waves done reading before overwrite
    }

    // ---- epilogue: C/D layout col=lane&15, row=(lane>>4)*4+reg ----
    const int col0 = lane & 15;
    const int row0 = (lane >> 4) * 4;
    #pragma unroll
    for (int i = 0; i < 4; ++i) {
        #pragma unroll
        for (int j = 0; j < 2; ++j) {
            const int m = m0 + wm + i * 16 + row0;
            const int n = n0 + wn + j * 16 + col0;
            float* o = out + (size_t)m * (L_ * HW_) + (size_t)l * HW_ + n;
            #pragma unroll
            for (int r = 0; r < 4; ++r)
                o[(size_t)r * (L_ * HW_)] = acc[i][j][r];
        }
    }
}

extern "C" void kernel_launch(void* const* d_in, const int* in_sizes, int n_in,
                              void* d_out, int out_size, void* d_ws, size_t ws_size,
                              hipStream_t stream) {
    const float* code = (const float*)d_in[0];   // [256, 64, 256] fp32
    const float* W    = (const float*)d_in[1];   // [64, 256, 1024] fp32
    float* out        = (float*)d_out;           // [256, 64, 32, 32] fp32

    gld_mfma_kernel<<<dim3(1024), 512, 0, stream>>>(code, W, out);
}

// Round 5
// 132.120 us; speedup vs baseline: 1.2093x; 1.2093x over previous
//
#include <hip/hip_runtime.h>
#include <hip/hip_bf16.h>

// Problem: out[b,l,:] = code[b,l,:] @ W[l]   (B=256, L=64, C=256, HW=1024, fp32)
#define B_  256
#define L_  64
#define C_  256
#define HW_ 1024

typedef float  floatx4 __attribute__((ext_vector_type(4)));
typedef __bf16 bf16x8  __attribute__((ext_vector_type(8)));
typedef __bf16 bf16x4  __attribute__((ext_vector_type(4)));

#define LDT_A 72    // A row stride in bf16 (144 B): A write/read banks uniform (verified R0)
#define LDB_ROW 128 // B row stride in BYTES (64 bf16; banks handled by XOR swizzle, verified R0)

// Barrier that does NOT drain outstanding global loads (vmcnt): only LDS ops
// must be visible across the barrier; register prefetch stays in flight.
#define BARRIER_LDS() asm volatile("s_waitcnt lgkmcnt(0)\n\ts_barrier" ::: "memory")

// B LDS XOR swizzle (verified R0): element (n,k) at byte
//   n*128 + ((c16 ^ g(n))*16) + (2k mod 16),  c16 = k/8,  g(n) = (n ^ (n>>2)) & 7
__device__ __forceinline__ int bswz(int n) { return (n ^ (n >> 2)) & 7; }

// ROUND 5: R0 geometry + double-buffered LDS + ONE barrier per phase.
// Evidence: R4 spilled (kill-criterion: WRITE +63 MB) -> BK=128 untested and
// abandoned; R0 runs at 6.15 TB/s load-stream vs the 8.0 TB/s R2 demonstrated,
// i.e. 30% over its own 33.5us byte-floor. R1 proved ISSUE slack is not the
// binding term; what R0/R1 both retain is that each phase's COMPUTE sits
// behind that phase's load arrival (stage -> barrier -> compute), so all 8
// waves lockstep on the load-latency tail every phase. Fix: ping-pong LDS
// buffers; phase t = { issue L(t+1); compute tile t-1 from buf[(t-1)&1]
// (independent of in-flight loads); stage tile t into buf[t&1] behind a
// compiler-counted vmcnt; one lgkm-only barrier }. Phase time becomes
// max(load tail, compute+writes) instead of the sum.
// Registers: R1's measured-no-spill layout (Areg[2][4]+Breg[2][4]=64 VGPR).
// LDS: 2*(18+16) KB = 68 KB -> still 2 blocks/CU (136 < 160).

__device__ __forceinline__ void compute_tile(const __bf16* __restrict__ Albuf,
                                             const unsigned char* __restrict__ Blbuf,
                                             floatx4 (&acc)[4][2],
                                             int lane, int wm, int wn)
{
    #pragma unroll
    for (int ks = 0; ks < 2; ++ks) {
        bf16x8 af[4], bfr[2];
        const int koff = ks * 32 + (lane >> 4) * 8;
        #pragma unroll
        for (int i = 0; i < 4; ++i)
            af[i] = *(const bf16x8*)&Albuf[(wm + i * 16 + (lane & 15)) * LDT_A + koff];
        #pragma unroll
        for (int j = 0; j < 2; ++j) {
            const int n = wn + j * 16 + (lane & 15);
            bfr[j] = *(const bf16x8*)&Blbuf[n * LDB_ROW + (((koff >> 3) ^ bswz(n)) << 4)];
        }
        #pragma unroll
        for (int i = 0; i < 4; ++i)
            #pragma unroll
            for (int j = 0; j < 2; ++j)
                acc[i][j] = __builtin_amdgcn_mfma_f32_16x16x32_bf16(af[i], bfr[j], acc[i][j], 0, 0, 0);
    }
}

__global__ __launch_bounds__(512, 4)
void gld_mfma_kernel(const float* __restrict__ code,
                     const float* __restrict__ W,
                     float* __restrict__ out)
{
    const int tid = threadIdx.x;

    // XCD swizzle (as R0): id = ll + 8*(m + 2n + 16*lh), l = 8*lh + ll.
    const int id  = blockIdx.x;
    const int ll  = id & 7;
    const int inr = id >> 3;
    const int m0  = (inr & 1) * 128;        // batch rows
    const int n0  = ((inr >> 1) & 7) * 128; // HW cols
    const int l   = (inr >> 4) * 8 + ll;    // filter

    __shared__ __bf16 Alds[2][128 * LDT_A];           // ping-pong A tiles (2 x 18 KB)
    __shared__ unsigned char Blds[2][128 * LDB_ROW];  // ping-pong B tiles (2 x 16 KB)

    const int lane = tid & 63;
    const int wave = tid >> 6;          // 0..7
    const int wm = (wave >> 2) * 64;    // 0,64
    const int wn = (wave & 3) * 32;     // 0,32,64,96

    floatx4 acc[4][2];
    #pragma unroll
    for (int i = 0; i < 4; ++i)
        #pragma unroll
        for (int j = 0; j < 2; ++j)
            acc[i][j] = (floatx4)0.0f;

    // A staging: 128 rows x 64 k fp32 -> 4 float4 per thread (coalesced)
    const int a_row = tid >> 4;          // 0..31 (4 passes of 32 rows)
    const int a_kc  = (tid & 15) * 4;    // k-chunk
    // B staging: thread owns a 4n x 4k micro-tile; 4 float4 loads of
    // consecutive n at 4 consecutive k-rows (2 x 512 B runs per instr).
    const int b_i  = tid & 31;           // n-quad (n = 4*b_i + j)
    const int b_c8 = tid >> 5;           // 8B k-chunk 0..15 (k = 4*b_c8 ..+3)

    const float* aBase = code + (size_t)m0 * (L_ * C_) + (size_t)l * C_ + a_kc;
    const float* wBase = W + (size_t)l * (C_ * HW_) + (size_t)(4 * b_c8) * HW_ + n0 + 4 * b_i;

    floatx4 Areg[2][4];   // reg set s holds tile t with s = t&1
    floatx4 Breg[2][4];

    // ---- prologue: L(0) -> set 0 ----
    #pragma unroll
    for (int p = 0; p < 4; ++p)
        Areg[0][p] = *(const floatx4*)(aBase + (size_t)(p * 32 + a_row) * (L_ * C_));
    #pragma unroll
    for (int r = 0; r < 4; ++r)
        Breg[0][r] = *(const floatx4*)(wBase + (size_t)r * HW_);

    // B LDS write addresses (loop-invariant): row 4*b_i+j, 8B chunk b_c8
    int bwaddr[4];
    #pragma unroll
    for (int j = 0; j < 4; ++j) {
        const int row = 4 * b_i + j;
        bwaddr[j] = row * LDB_ROW + (((b_c8 >> 1) ^ bswz(row)) << 4) + ((b_c8 & 1) << 3);
    }

    // ---- pipelined main loop: 4 phases + compute tail ----
    #pragma unroll
    for (int t = 0; t < 4; ++t) {               // fully unrolled: s, kb compile-time
        const int s  = t & 1;
        const int kb = t * 64;

        // (1) issue L(t+1) into the other reg set (younger than everything;
        //     stays in flight across the vmcnt wait in (3) and the barrier).
        if (t < 3) {
            #pragma unroll
            for (int p = 0; p < 4; ++p)
                Areg[s ^ 1][p] = *(const floatx4*)(aBase + (size_t)(p * 32 + a_row) * (L_ * C_) + (kb + 64));
            #pragma unroll
            for (int r = 0; r < 4; ++r)
                Breg[s ^ 1][r] = *(const floatx4*)(wBase + (size_t)(kb + 64 + r) * HW_);
        }

        // (2) compute tile t-1 from the OTHER buffer — independent of this
        //     phase's in-flight loads, so MFMA proceeds while L(t) drains.
        if (t > 0)
            compute_tile(Alds[s ^ 1], Blds[s ^ 1], acc, lane, wm, wn);

        // (3) stage tile t -> buf s. The ds_writes carry a compiler-counted
        //     vmcnt (waits L(t) only; L(t+1) stays outstanding).
        #pragma unroll
        for (int j = 0; j < 4; ++j) {
            bf16x4 h;
            h.x = (__bf16)Breg[s][0][j]; h.y = (__bf16)Breg[s][1][j];
            h.z = (__bf16)Breg[s][2][j]; h.w = (__bf16)Breg[s][3][j];
            *(bf16x4*)&Blds[s][bwaddr[j]] = h;
        }
        #pragma unroll
        for (int p = 0; p < 4; ++p) {
            bf16x4 h;
            h.x = (__bf16)Areg[s][p].x; h.y = (__bf16)Areg[s][p].y;
            h.z = (__bf16)Areg[s][p].z; h.w = (__bf16)Areg[s][p].w;
            *(bf16x4*)&Alds[s][(p * 32 + a_row) * LDT_A + a_kc] = h;
        }

        // (4) ONE barrier per phase: makes buf s visible for phase t+1 and
        //     fences readers of buf s^1 before it is overwritten in t+1.
        BARRIER_LDS();
    }

    // ---- tail: compute tile 3 (staged in phase 3 into buf 1) ----
    compute_tile(Alds[1], Blds[1], acc, lane, wm, wn);

    // ---- epilogue: C/D layout col=lane&15, row=(lane>>4)*4+reg ----
    const int col0 = lane & 15;
    const int row0 = (lane >> 4) * 4;
    #pragma unroll
    for (int i = 0; i < 4; ++i) {
        #pragma unroll
        for (int j = 0; j < 2; ++j) {
            const int m = m0 + wm + i * 16 + row0;
            const int n = n0 + wn + j * 16 + col0;
            float* o = out + (size_t)m * (L_ * HW_) + (size_t)l * HW_ + n;
            #pragma unroll
            for (int r = 0; r < 4; ++r)
                o[(size_t)r * (L_ * HW_)] = acc[i][j][r];
        }
    }
}

extern "C" void kernel_launch(void* const* d_in, const int* in_sizes, int n_in,
                              void* d_out, int out_size, void* d_ws, size_t ws_size,
                              hipStream_t stream) {
    const float* code = (const float*)d_in[0];   // [256, 64, 256] fp32
    const float* W    = (const float*)d_in[1];   // [64, 256, 1024] fp32
    float* out        = (float*)d_out;           // [256, 64, 32, 32] fp32

    gld_mfma_kernel<<<dim3(1024), 512, 0, stream>>>(code, W, out);
}

// Round 6
// 129.954 us; speedup vs baseline: 1.2294x; 1.0167x over previous
//
#include <hip/hip_runtime.h>
#include <hip/hip_bf16.h>

// Problem: out[b,l,:] = code[b,l,:] @ W[l]   (B=256, L=64, C=256, HW=1024, fp32)
#define B_  256
#define L_  64
#define C_  256
#define HW_ 1024

typedef float  floatx4 __attribute__((ext_vector_type(4)));
typedef __bf16 bf16x8  __attribute__((ext_vector_type(8)));
typedef __bf16 bf16x4  __attribute__((ext_vector_type(4)));
typedef __bf16 bf16x2  __attribute__((ext_vector_type(2)));

#define LDT_A 72    // A row stride in bf16 (144 B): A write/read banks uniform (verified R0)
#define LDB_ROW 128 // B row stride in BYTES (64 bf16; banks handled by XOR swizzle, verified R0)

// Barrier that does NOT drain outstanding global loads (vmcnt): only LDS ops
// must be visible across the barrier; register prefetch stays in flight.
#define BARRIER_LDS() asm volatile("s_waitcnt lgkmcnt(0)\n\ts_barrier" ::: "memory")

// B LDS XOR swizzle (verified R0/R2): element (n,k) at byte
//   n*128 + ((c16 ^ g(n))*16) + (2k mod 16),  c16 = k/8,  g(n) = (n ^ (n>>2)) & 7
__device__ __forceinline__ int bswz(int n) { return (n ^ (n >> 2)) & 7; }

// ROUND 6: byte x wave optimization. Model fitted to R0-R5 (all scheduling
// nulls): every config sustains ~1 B/cycle/WAVE of load return regardless of
// pipelining -> time ~ load_bytes / (waves_per_CU * 2.2 GB/s).
//   R0: 268 MB, 9.6 waves -> 43.6us.  R3: 134 MB, 5.5 waves -> 48us.
// This round moves BOTH terms favorably: tile 256x128 (BM = whole batch ->
// W read ONCE: loads = 16.8*8 + 67 = 201 MB, -25%) with 1024-thread blocks
// (16 waves/CU resident, = R0's effective best). Wave-tile 64x32 keeps
// acc[4][2] = 32 AGPR (R0-proven; avoids R3/R4's register trap). Staging
// A 4 + B 2 float4/thread (= R5's proven-no-spill budget). LDS double-
// buffered 104 KB -> 1 block/CU of 16 waves. Grid 512 = 2 generations.
// Loop skeleton = R5 (neutral there, and with 1-block residency the
// compute/stage overlap is the only cross-phase overlap available).

__device__ __forceinline__ void compute_tile(const __bf16* __restrict__ Albuf,
                                             const unsigned char* __restrict__ Blbuf,
                                             floatx4 (&acc)[4][2],
                                             int lane, int wm, int wn)
{
    #pragma unroll
    for (int ks = 0; ks < 2; ++ks) {
        bf16x8 af[4], bfr[2];
        const int koff = ks * 32 + (lane >> 4) * 8;
        #pragma unroll
        for (int i = 0; i < 4; ++i)
            af[i] = *(const bf16x8*)&Albuf[(wm + i * 16 + (lane & 15)) * LDT_A + koff];
        #pragma unroll
        for (int j = 0; j < 2; ++j) {
            const int n = wn + j * 16 + (lane & 15);
            bfr[j] = *(const bf16x8*)&Blbuf[n * LDB_ROW + (((koff >> 3) ^ bswz(n)) << 4)];
        }
        #pragma unroll
        for (int i = 0; i < 4; ++i)
            #pragma unroll
            for (int j = 0; j < 2; ++j)
                acc[i][j] = __builtin_amdgcn_mfma_f32_16x16x32_bf16(af[i], bfr[j], acc[i][j], 0, 0, 0);
    }
}

__global__ __launch_bounds__(1024, 4)
void gld_mfma_kernel(const float* __restrict__ code,
                     const float* __restrict__ W,
                     float* __restrict__ out)
{
    const int tid = threadIdx.x;

    // XCD swizzle: id = ll + 8*(n_idx + 8*lh), l = 8*lh + ll. All 8 n-blocks
    // of filter l share id%8 -> same XCD; they share the code[:,l,:] panel
    // (the 8x-amplified operand) so re-reads are XCD-L2 hits.
    const int id   = blockIdx.x;
    const int ll   = id & 7;
    const int rest = id >> 3;                // 0..63
    const int n0   = (rest & 7) * 128;       // HW cols (8 slices of 128)
    const int l    = (rest >> 3) * 8 + ll;   // filter

    __shared__ __bf16 Alds[2][256 * LDT_A];           // ping-pong A tiles (2 x 36 KB)
    __shared__ unsigned char Blds[2][128 * LDB_ROW];  // ping-pong B tiles (2 x 16 KB)

    const int lane = tid & 63;
    const int wave = tid >> 6;          // 0..15
    const int wm = (wave >> 2) * 64;    // 0,64,128,192 (m offset of wave)
    const int wn = (wave & 3) * 32;     // 0,32,64,96   (n offset of wave)

    floatx4 acc[4][2];
    #pragma unroll
    for (int i = 0; i < 4; ++i)
        #pragma unroll
        for (int j = 0; j < 2; ++j)
            acc[i][j] = (floatx4)0.0f;

    // A staging: 256 rows x 64 k fp32 -> 4 float4/thread (4 passes of 64 rows;
    // per instr: 4 rows x 256 B runs, fully coalesced -- R0's exact pattern).
    const int a_row = tid >> 4;          // 0..63
    const int a_kc  = (tid & 15) * 4;    // k-chunk
    // B staging: 64 k-rows x 128 n fp32 -> 2 float4/thread. Thread owns a
    // 4n x 2k micro-tile; per instr 2 x 512 B runs (R2's verified pattern).
    const int b_i = tid & 31;            // n-quad (n = 4*b_i + j, 0..127)
    const int b_k = tid >> 5;            // k-pair index 0..31 (k = 2*b_k, +1)

    const float* aBase = code + (size_t)l * C_ + a_kc;
    const float* wBase = W + (size_t)l * (C_ * HW_) + (size_t)(2 * b_k) * HW_ + n0 + 4 * b_i;

    floatx4 Areg[2][4];   // reg set s holds tile t with s = t&1
    floatx4 Breg[2][2];

    // ---- prologue: L(0) -> set 0 ----
    #pragma unroll
    for (int p = 0; p < 4; ++p)
        Areg[0][p] = *(const floatx4*)(aBase + (size_t)(p * 64 + a_row) * (L_ * C_));
    #pragma unroll
    for (int r = 0; r < 2; ++r)
        Breg[0][r] = *(const floatx4*)(wBase + (size_t)r * HW_);

    // B LDS write addresses (loop-invariant): row 4*b_i+j holds k-pair 2*b_k
    // at byte row*128 + (((b_k>>2) ^ g(row))<<4) + ((b_k&3)<<2)  (R2 formula)
    int bwaddr[4];
    #pragma unroll
    for (int j = 0; j < 4; ++j) {
        const int row = 4 * b_i + j;
        bwaddr[j] = row * LDB_ROW + (((b_k >> 2) ^ bswz(row)) << 4) + ((b_k & 3) << 2);
    }

    // ---- pipelined main loop: 4 phases + compute tail (R5 skeleton) ----
    #pragma unroll
    for (int t = 0; t < 4; ++t) {               // fully unrolled: s, kb compile-time
        const int s  = t & 1;
        const int kb = t * 64;

        // (1) issue L(t+1) into the other reg set (stays in flight across
        //     the vmcnt wait in (3) and the barrier).
        if (t < 3) {
            #pragma unroll
            for (int p = 0; p < 4; ++p)
                Areg[s ^ 1][p] = *(const floatx4*)(aBase + (size_t)(p * 64 + a_row) * (L_ * C_) + (kb + 64));
            #pragma unroll
            for (int r = 0; r < 2; ++r)
                Breg[s ^ 1][r] = *(const floatx4*)(wBase + (size_t)(kb + 64 + r) * HW_);
        }

        // (2) compute tile t-1 from the OTHER buffer — independent of this
        //     phase's in-flight loads.
        if (t > 0)
            compute_tile(Alds[s ^ 1], Blds[s ^ 1], acc, lane, wm, wn);

        // (3) stage tile t -> buf s (ds_writes carry a compiler-counted
        //     vmcnt: waits L(t) only; L(t+1) stays outstanding).
        #pragma unroll
        for (int j = 0; j < 4; ++j) {
            bf16x2 h;
            h.x = (__bf16)Breg[s][0][j];    // k = 2*b_k
            h.y = (__bf16)Breg[s][1][j];    // k = 2*b_k + 1
            *(bf16x2*)&Blds[s][bwaddr[j]] = h;
        }
        #pragma unroll
        for (int p = 0; p < 4; ++p) {
            bf16x4 h;
            h.x = (__bf16)Areg[s][p].x; h.y = (__bf16)Areg[s][p].y;
            h.z = (__bf16)Areg[s][p].z; h.w = (__bf16)Areg[s][p].w;
            *(bf16x4*)&Alds[s][(p * 64 + a_row) * LDT_A + a_kc] = h;
        }

        // (4) ONE barrier per phase.
        BARRIER_LDS();
    }

    // ---- tail: compute tile 3 (staged in phase 3 into buf 1) ----
    compute_tile(Alds[1], Blds[1], acc, lane, wm, wn);

    // ---- epilogue: C/D layout col=lane&15, row=(lane>>4)*4+reg ----
    const int col0 = lane & 15;
    const int row0 = (lane >> 4) * 4;
    #pragma unroll
    for (int i = 0; i < 4; ++i) {
        #pragma unroll
        for (int j = 0; j < 2; ++j) {
            const int m = wm + i * 16 + row0;              // BM = whole batch
            const int n = n0 + wn + j * 16 + col0;
            float* o = out + (size_t)m * (L_ * HW_) + (size_t)l * HW_ + n;
            #pragma unroll
            for (int r = 0; r < 4; ++r)
                o[(size_t)r * (L_ * HW_)] = acc[i][j][r];
        }
    }
}

extern "C" void kernel_launch(void* const* d_in, const int* in_sizes, int n_in,
                              void* d_out, int out_size, void* d_ws, size_t ws_size,
                              hipStream_t stream) {
    const float* code = (const float*)d_in[0];   // [256, 64, 256] fp32
    const float* W    = (const float*)d_in[1];   // [64, 256, 1024] fp32
    float* out        = (float*)d_out;           // [256, 64, 32, 32] fp32

    gld_mfma_kernel<<<dim3(512), 1024, 0, stream>>>(code, W, out);
}

// Round 7
// 124.700 us; speedup vs baseline: 1.2812x; 1.0421x over previous
//
#include <hip/hip_runtime.h>
#include <hip/hip_bf16.h>

// Problem: out[b,l,:] = code[b,l,:] @ W[l]   (B=256, L=64, C=256, HW=1024, fp32)
#define B_  256
#define L_  64
#define C_  256
#define HW_ 1024

typedef float  floatx4 __attribute__((ext_vector_type(4)));
typedef __bf16 bf16x8  __attribute__((ext_vector_type(8)));
typedef __bf16 bf16x4  __attribute__((ext_vector_type(4)));
typedef __bf16 bf16x2  __attribute__((ext_vector_type(2)));

#define LDA_ROW 80   // A row stride BYTES (40 bf16 = 32 k + pad; 16B-aligned rows, 2-way read = free)
#define LDB_ROW 64   // B row stride BYTES (32 bf16; 2-bit XOR chunk swizzle)

// Barrier that does NOT drain outstanding global loads (vmcnt): only LDS ops
// must be visible across the barrier; register prefetch stays in flight.
#define BARRIER_LDS() asm volatile("s_waitcnt lgkmcnt(0)\n\ts_barrier" ::: "memory")

// B LDS swizzle (2-bit variant of the R0-verified scheme): element (n,k) at
//   byte n*64 + ((c16 ^ g2(n))<<4) + (2k mod 16),  c16 = k>>3,
//   g2(n) = (n ^ (n>>2)) & 3.
// Reads (bf16x8, 16 lanes at rows base..base+15, fixed c16): bank
// 16(n&1)+4*(c16^g2(n)) -> every bank exactly 2 lanes = free (m136).
// Writes (bf16x2, 4/thread/phase): ~16-way on 4 b32s -- accepted, monitored.
__device__ __forceinline__ int g2(int n) { return (n ^ (n >> 2)) & 3; }

// ROUND 7: 256x256 tile (issued loads 134 MB = this family's floor) at 16
// waves/block with the R5 dbuf pipeline. Model validated by R6: time ~
// issued_load_bytes / ~6.6 TB/s effective supply (R6's total traffic ran
// exactly at the fillBuffer-demonstrated 6.6 TB/s). R3 already had 134 MB but
// died from 8-wave/128-AGPR blocks + serial stage->barrier->compute; here:
// wave-tile 64x64 (acc[4][4]=64 regs), BK=32 so ping-pong staging fits
// (regs ~115 < 128 -> 4 waves/SIMD), R5 skeleton so compute(t-1) overlaps
// L(t) drain -- the only overlap available at 1 block/CU. Grid 256 = 1/CU.
__global__ __launch_bounds__(1024, 4)
void gld_mfma_kernel(const float* __restrict__ code,
                     const float* __restrict__ W,
                     float* __restrict__ out)
{
    const int tid = threadIdx.x;

    // XCD swizzle: id = ll + 8*(n_idx + 4*lh), l = 8*lh + ll. The 4 n-blocks
    // of filter l share id%8 -> same XCD; they share the code[:,l,:] panel
    // (the 4x-amplified operand) so re-reads are XCD-L2 hits.
    const int id   = blockIdx.x;
    const int ll   = id & 7;
    const int rest = id >> 3;                // 0..31
    const int n0   = (rest & 3) * 256;       // HW cols (4 slices of 256)
    const int l    = (rest >> 2) * 8 + ll;   // filter

    __shared__ unsigned char Alds[2][256 * LDA_ROW];  // ping-pong A tiles (2 x 20 KB)
    __shared__ unsigned char Blds[2][256 * LDB_ROW];  // ping-pong B tiles (2 x 16 KB)

    const int lane = tid & 63;
    const int wave = tid >> 6;          // 0..15
    const int wm = (wave >> 2) * 64;    // m offset of wave (4 m-waves)
    const int wn = (wave & 3) * 64;     // n offset of wave (4 n-waves)

    floatx4 acc[4][4];
    #pragma unroll
    for (int i = 0; i < 4; ++i)
        #pragma unroll
        for (int j = 0; j < 4; ++j)
            acc[i][j] = (floatx4)0.0f;

    // A staging: 256 rows x 32 k fp32 = 8 fp32/thread (2 float4).
    // a_row = tid>>2 (0..255), k = 4*(tid&3) and +16. Per instr: 16 rows x
    // 64 B contiguous runs (4 lanes/row); instr pair covers full 128-B lines.
    const int a_row = tid >> 2;
    const int a_k4  = (tid & 3) * 4;
    // B staging: 32 k-rows x 256 n fp32 = 8 fp32/thread (2 float4).
    // Wave w owns k-rows 2w, 2w+1; lane owns n-quad 4*lane. Per instr: the
    // wave covers one full 1024-B W row (fully coalesced).
    const int b_i = tid & 63;            // n-quad (n = 4*b_i + j)

    const float* aBase = code + (size_t)l * C_ + a_k4;
    const float* wBase = W + (size_t)l * (C_ * HW_) + (size_t)(2 * wave) * HW_ + n0 + 4 * b_i;

    floatx4 Areg[2][2];   // reg set s holds tile t with s = t&1
    floatx4 Breg[2][2];

    // ---- prologue: L(0) -> set 0 ----
    Areg[0][0] = *(const floatx4*)(aBase + (size_t)a_row * (L_ * C_));
    Areg[0][1] = *(const floatx4*)(aBase + (size_t)a_row * (L_ * C_) + 16);
    #pragma unroll
    for (int r = 0; r < 2; ++r)
        Breg[0][r] = *(const floatx4*)(wBase + (size_t)r * HW_);

    // B LDS write addresses (loop-invariant): row 4*b_i+j holds k-pair 2w at
    // byte row*64 + (((w>>2) ^ g2(row))<<4) + ((w&3)<<2)
    int bwaddr[4];
    #pragma unroll
    for (int j = 0; j < 4; ++j) {
        const int row = 4 * b_i + j;
        bwaddr[j] = row * LDB_ROW + ((((wave >> 2) ^ g2(row))) << 4) + ((wave & 3) << 2);
    }
    // A LDS write byte (loop-invariant part): row*80 + 2*a_k4 (and +32)
    const int awaddr = a_row * LDA_ROW + 2 * a_k4;

    // ---- pipelined main loop: 8 phases (BK=32) + compute tail ----
    #pragma unroll
    for (int t = 0; t < 8; ++t) {               // fully unrolled: s, kb compile-time
        const int s  = t & 1;
        const int kb = t * 32;

        // (1) issue L(t+1) into the other reg set (stays in flight across
        //     the vmcnt wait in (3) and the barrier).
        if (t < 7) {
            Areg[s ^ 1][0] = *(const floatx4*)(aBase + (size_t)a_row * (L_ * C_) + (kb + 32));
            Areg[s ^ 1][1] = *(const floatx4*)(aBase + (size_t)a_row * (L_ * C_) + (kb + 48));
            #pragma unroll
            for (int r = 0; r < 2; ++r)
                Breg[s ^ 1][r] = *(const floatx4*)(wBase + (size_t)(kb + 32 + r) * HW_);
        }

        // (2) compute tile t-1 from the OTHER buffer — independent of this
        //     phase's in-flight loads; MFMA proceeds while L(t) drains.
        if (t > 0) {
            const unsigned char* Ab = Alds[s ^ 1];
            const unsigned char* Bb = Blds[s ^ 1];
            bf16x8 af[4], bfr[4];
            const int c16 = lane >> 4;                    // k-chunk 0..3
            #pragma unroll
            for (int i = 0; i < 4; ++i)
                af[i] = *(const bf16x8*)&Ab[(wm + i * 16 + (lane & 15)) * LDA_ROW + c16 * 16];
            #pragma unroll
            for (int j = 0; j < 4; ++j) {
                const int n = wn + j * 16 + (lane & 15);
                bfr[j] = *(const bf16x8*)&Bb[n * LDB_ROW + ((c16 ^ g2(n)) << 4)];
            }
            #pragma unroll
            for (int i = 0; i < 4; ++i)
                #pragma unroll
                for (int j = 0; j < 4; ++j)
                    acc[i][j] = __builtin_amdgcn_mfma_f32_16x16x32_bf16(af[i], bfr[j], acc[i][j], 0, 0, 0);
        }

        // (3) stage tile t -> buf s (ds_writes carry a compiler-counted
        //     vmcnt: waits L(t) only; L(t+1) stays outstanding).
        #pragma unroll
        for (int j = 0; j < 4; ++j) {
            bf16x2 h;
            h.x = (__bf16)Breg[s][0][j];    // k = 2*wave
            h.y = (__bf16)Breg[s][1][j];    // k = 2*wave + 1
            *(bf16x2*)&Blds[s][bwaddr[j]] = h;
        }
        #pragma unroll
        for (int p = 0; p < 2; ++p) {
            bf16x4 h;
            h.x = (__bf16)Areg[s][p].x; h.y = (__bf16)Areg[s][p].y;
            h.z = (__bf16)Areg[s][p].z; h.w = (__bf16)Areg[s][p].w;
            *(bf16x4*)&Alds[s][awaddr + p * 32] = h;
        }

        // (4) ONE barrier per phase.
        BARRIER_LDS();
    }

    // ---- tail: compute tile 7 (staged in phase 7 into buf 1) ----
    {
        const unsigned char* Ab = Alds[1];
        const unsigned char* Bb = Blds[1];
        bf16x8 af[4], bfr[4];
        const int c16 = lane >> 4;
        #pragma unroll
        for (int i = 0; i < 4; ++i)
            af[i] = *(const bf16x8*)&Ab[(wm + i * 16 + (lane & 15)) * LDA_ROW + c16 * 16];
        #pragma unroll
        for (int j = 0; j < 4; ++j) {
            const int n = wn + j * 16 + (lane & 15);
            bfr[j] = *(const bf16x8*)&Bb[n * LDB_ROW + ((c16 ^ g2(n)) << 4)];
        }
        #pragma unroll
        for (int i = 0; i < 4; ++i)
            #pragma unroll
            for (int j = 0; j < 4; ++j)
                acc[i][j] = __builtin_amdgcn_mfma_f32_16x16x32_bf16(af[i], bfr[j], acc[i][j], 0, 0, 0);
    }

    // ---- epilogue: C/D layout col=lane&15, row=(lane>>4)*4+reg ----
    const int col0 = lane & 15;
    const int row0 = (lane >> 4) * 4;
    #pragma unroll
    for (int i = 0; i < 4; ++i) {
        #pragma unroll
        for (int j = 0; j < 4; ++j) {
            const int m = wm + i * 16 + row0;              // BM = whole batch
            const int n = n0 + wn + j * 16 + col0;
            float* o = out + (size_t)m * (L_ * HW_) + (size_t)l * HW_ + n;
            #pragma unroll
            for (int r = 0; r < 4; ++r)
                o[(size_t)r * (L_ * HW_)] = acc[i][j][r];
        }
    }
}

extern "C" void kernel_launch(void* const* d_in, const int* in_sizes, int n_in,
                              void* d_out, int out_size, void* d_ws, size_t ws_size,
                              hipStream_t stream) {
    const float* code = (const float*)d_in[0];   // [256, 64, 256] fp32
    const float* W    = (const float*)d_in[1];   // [64, 256, 1024] fp32
    float* out        = (float*)d_out;           // [256, 64, 32, 32] fp32

    gld_mfma_kernel<<<dim3(256), 1024, 0, stream>>>(code, W, out);
}